// Round 8
// baseline (309.742 us; speedup 1.0000x reference)
//
#include <hip/hip_runtime.h>
#include <math.h>

#define BB 2
#define LSEQ 2048
#define H 32
#define PDIM 64
#define NDIM 128
#define CS 256
#define NC 8
#define MAGIC 0x1F2E3D4C

typedef _Float16 half8 __attribute__((ext_vector_type(8)));
typedef _Float16 half4 __attribute__((ext_vector_type(4)));
typedef float floatx4 __attribute__((ext_vector_type(4)));

// ---------------- ws layout (bytes) ----------------
// cum      : f32 [bz=16][H][CS]               @ 0         (512 KB)
// cA       : f32 [bz][H][CS]  (dtf*xs)        @ 524288    (512 KB)
// cdecay   : f32 [bz][H]                      @ 1048576   (2 KB)
// CBh      : f16 [bz][l16=16][s8=32][16][8]   @ 1050624   (2 MB)
// statesF16: f16 [bzh][8192] tiled /16        @ 3147776   (8 MB)
// Bt16T    : f16 [bz][n16=8][s8=32][16][8]    @ 19924992  (1 MB)
// C16T     : f16 [bz][l16=16][n8=16][16][8]   @ 20973568  (1 MB)
// x8       : i8  [b][l][h][p]                 @ 22022144  (8 MB)
// fA1      : i32 [256]                        @ 30410752  (1 KB)   flags
// f013     : i32 [1024]                       @ 30411776  (4 KB)   flags
// fA2      : i32 [416]                        @ 30415872  (1.6 KB) flags
// Flags are re-poisoned by the harness fill each rep (fill covers whole ws);
// MAGIC has 4 distinct bytes so no repeated-byte poison pattern can alias it.

__device__ __forceinline__ int dot4i8(int a, int b, int c) {
#if __has_builtin(__builtin_amdgcn_sdot4)
    return __builtin_amdgcn_sdot4(a, b, c, false);
#else
    c += ((a << 24) >> 24) * ((b << 24) >> 24);
    c += ((a << 16) >> 24) * ((b << 16) >> 24);
    c += ((a << 8) >> 24) * ((b << 8) >> 24);
    c += (a >> 24) * (b >> 24);
    return c;
#endif
}

__device__ __forceinline__ void spin_eq(const int* p, int magic) {
    while (__hip_atomic_load(p, __ATOMIC_ACQUIRE, __HIP_MEMORY_SCOPE_AGENT) != magic)
        __builtin_amdgcn_s_sleep(4);
}

__device__ __forceinline__ void publish(int* p, int t) {
    __syncthreads();
    if (t == 0) {
        __threadfence();
        __hip_atomic_store(p, (int)MAGIC, __ATOMIC_RELEASE, __HIP_MEMORY_SCOPE_AGENT);
    }
}

// kMega: all four stages in ONE dispatch, ordered so consumers only wait on
// strictly lower block indices (in-order WG dispatch => deadlock-free):
//   [0,256)     kA1  : Bt16T transpose            -> fA1[blockIdx]
//   [256,1280)  k013 : scan + x stage + states    (spins fA1 before MFMA) -> f013
//   [1280,1696) kA2  : CBh Gram + C16T            -> fA2
//   [1696,2720) k56  : inter(z-scan)+intra+D      (spins f013 + fA2 at entry)
#define P16_STRIDE 4360
#define XT_PITCH 136
__global__ __launch_bounds__(256, 4) void kMega(
    const int* __restrict__ dt, const int* __restrict__ qA, const float* __restrict__ dt_bias,
    const float* __restrict__ A_scale_p, const float* __restrict__ dt_scale_p,
    const int* __restrict__ xq, const float* __restrict__ xs_p, const float* __restrict__ Bs_p,
    const int* __restrict__ Bm, const int* __restrict__ Cm, const float* __restrict__ Cs_p,
    const int* __restrict__ qD, const float* __restrict__ Ds_p,
    float* __restrict__ cum, float* __restrict__ cAg, float* __restrict__ cdecay,
    signed char* __restrict__ x8, _Float16* __restrict__ statesF16,
    _Float16* __restrict__ Bt16T, _Float16* __restrict__ CBh, _Float16* __restrict__ C16T,
    int* __restrict__ fA1, int* __restrict__ f013, int* __restrict__ fA2,
    float* __restrict__ out)
{
    __shared__ __align__(16) char USH[35840];   // union of all family LDS needs
    int t = threadIdx.x;

    if (blockIdx.x < 256) {
        // ================= kA1: Bt16T transpose =================
        int slice = blockIdx.x & 15;
        int zz = blockIdx.x >> 4;
        int z = zz & 7, b = zz >> 3;
        int bz = b * NC + z;
        int nm = t & 15, s8l = t >> 4;
        int n16 = slice & 7, s8 = (slice >> 3) * 16 + s8l;
        const int* bp = Bm + (size_t)(b * LSEQ + z * CS + s8 * 8) * NDIM + n16 * 16 + nm;
        half8 v;
#pragma unroll
        for (int j = 0; j < 8; ++j) v[j] = (_Float16)(float)bp[(size_t)j * NDIM];
        *(half8*)(Bt16T + ((size_t)(bz * 8 + n16) * 32 + s8) * 128 + nm * 8) = v;
        publish(&fA1[blockIdx.x], t);
        return;
    }

    if (blockIdx.x < 1280) {
        // ================= k013 (round-5 verified body) =================
        int kb = blockIdx.x - 256;
        float* cumS   = (float*)USH;
        float* cB     = (float*)(USH + 1024);
        float* wsum   = (float*)(USH + 2048);
        _Float16* xcS = (_Float16*)(USH + 2064);
        int half = kb & 1;
        int id = kb >> 1;
        int h = id & 31, z = (id >> 5) & 7, b = id >> 8;
        int bz = b * NC + z, bzh = bz * H + h;
        int lane6 = t & 63, w = t >> 6;

        float A = -__expf((float)qA[h] * (*A_scale_p));
        float raw = (float)dt[(size_t)(b * LSEQ + z * CS + t) * H + h];
        float xin = raw * (*dt_scale_p) + dt_bias[h];
        float sp = (xin > 20.f) ? xin : log1pf(__expf(xin));
        float v = sp * A;
#pragma unroll
        for (int off = 1; off < 64; off <<= 1) {
            float u = __shfl_up(v, off, 64);
            if (lane6 >= off) v += u;
        }
        if (lane6 == 63) wsum[w] = v;
        __syncthreads();
        float add = 0.f;
        for (int wv = 0; wv < w; ++wv) add += wsum[wv];
        float cumv = v + add;
        float cl = wsum[0] + wsum[1] + wsum[2] + wsum[3];
        float xs = *xs_p;
        if (half == 0) {
            cum[(size_t)bzh * CS + t] = cumv;
            cAg[(size_t)bzh * CS + t] = sp * xs;
            if (t == 0) cdecay[bzh] = __expf(cl);
        }
        cumS[t] = cumv;
        cB[t] = sp * __expf(cl - cumv) * xs * (*Bs_p);
        __syncthreads();

        int pq = t & 7, srow = t >> 3;
        int p0 = half * 32 + pq * 4;
        const int* xb = xq + ((size_t)(b * LSEQ + z * CS) * H + h) * PDIM + p0;
        signed char* x8b = x8 + ((size_t)(b * LSEQ + z * CS) * H + h) * PDIM + p0;
        int plocal = pq * 4;
        int pbase = (plocal >> 4) * P16_STRIDE + ((plocal & 15) * 8);
        for (int j = 0; j < 8; ++j) {
            int s = j * 32 + srow;
            int4 w4 = *(const int4*)(xb + (size_t)s * (H * PDIM));
            float c = cB[s];
            int sbase = pbase + (s >> 3) * 136 + (s & 7);
            signed char pk[4];
            int xi[4] = {w4.x, w4.y, w4.z, w4.w};
#pragma unroll
            for (int pp = 0; pp < 4; ++pp) {
                xcS[sbase + pp * 8] = (_Float16)((float)xi[pp] * c);
                pk[pp] = (signed char)xi[pp];
            }
            *(int*)(x8b + (size_t)s * (H * PDIM)) = *(int*)pk;
        }
        __syncthreads();

        // wait for this bz's 16 Bt16T producer blocks (usually already done)
        if (t < 16) spin_eq(&fA1[(bz << 4) | t], MAGIC);
        __syncthreads();

        int m = lane6 & 15, q = lane6 >> 4;
        int p16l = w & 1, ntb = (w >> 1) * 4;
        const _Float16* abase = xcS + p16l * P16_STRIDE + m * 8;
        const _Float16* bbase = Bt16T + (size_t)(bz * 8) * 32 * 128 + m * 8;
        floatx4 acc[4] = {};
        for (int kk = 0; kk < 8; ++kk) {
            if (cl - cumS[kk * 32 + 31] < -30.f) continue;   // fp16-exact-0 chunk skip
            int s8k = kk * 4 + q;
            half8 a = *(const half8*)(abase + s8k * 136);
#pragma unroll
            for (int nt = 0; nt < 4; ++nt) {
                half8 bf = *(const half8*)(bbase + ((size_t)(ntb + nt) * 32 + s8k) * 128);
                acc[nt] = __builtin_amdgcn_mfma_f32_16x16x32_f16(a, bf, acc[nt], 0, 0, 0);
            }
        }
        int p16g = half * 2 + p16l;
        _Float16* sb = statesF16 + (size_t)bzh * 8192;
#pragma unroll
        for (int nt = 0; nt < 4; ++nt)
#pragma unroll
            for (int rr = 0; rr < 4; ++rr)
                sb[(size_t)(p16g * 16 + (ntb + nt) * 2 + (m >> 3)) * 128 + (q * 4 + rr) * 8 + (m & 7)] =
                    (_Float16)(acc[nt][rr] * 0.0625f);
        publish(&f013[kb], t);
        return;
    }

    if (blockIdx.x < 1696) {
        // ================= kA2: CBh Gram + C16T =================
        int bid2 = blockIdx.x - 1280;
        int (*Bi)[33] = (int(*)[33])USH;
        int (*Ci)[33] = (int(*)[33])(USH + 8448);
        int r = bid2 % 26;
        int zz = bid2 / 26;
        int z = zz & 7, b = zz >> 3;
        int bz = b * NC + z;
        if (r < 10) {
            const int LT[10] = {0,1,1,2,2,2,3,3,3,3};
            const int ST[10] = {0,0,1,0,1,2,0,1,2,3};
            int l0 = LT[r] * 64, s0 = ST[r] * 64;
            const int* Bp = Bm + (size_t)(b * LSEQ + z * CS + s0) * NDIM;
            const int* Cp = Cm + (size_t)(b * LSEQ + z * CS + l0) * NDIM;
            for (int i = t; i < 64 * 32; i += 256) {
                int rr = i >> 5, k = i & 31;
                const int* sb = Bp + rr * NDIM + k * 4;
                const int* sc = Cp + rr * NDIM + k * 4;
                Bi[rr][k] = (sb[0] & 255) | ((sb[1] & 255) << 8) | ((sb[2] & 255) << 16) | ((sb[3] & 255) << 24);
                Ci[rr][k] = (sc[0] & 255) | ((sc[1] & 255) << 8) | ((sc[2] & 255) << 16) | ((sc[3] & 255) << 24);
            }
            __syncthreads();
            float cbscale = (*Bs_p) * (*Cs_p);
            int ll = t & 63, lg = t >> 6;
            int acc[16];
#pragma unroll
            for (int i = 0; i < 16; ++i) acc[i] = 0;
            for (int k = 0; k < 32; ++k) {
                int cw = Ci[ll][k];
#pragma unroll
                for (int si = 0; si < 16; ++si)
                    acc[si] = dot4i8(cw, Bi[lg * 16 + si][k], acc[si]);
            }
            int l = l0 + ll;
            int l16 = l >> 4, lm = l & 15;
            int sb8 = (s0 + lg * 16) >> 3;
            _Float16* bp = CBh + ((size_t)(bz * 16 + l16) * 32 + sb8) * 128 + lm * 8;
#pragma unroll
            for (int g = 0; g < 2; ++g) {
                half8 v;
#pragma unroll
                for (int i = 0; i < 8; ++i) v[i] = (_Float16)((float)acc[g * 8 + i] * cbscale);
                *(half8*)(bp + g * 128) = v;
            }
        } else {
            int slice = r - 10;   // 0..15 -> C16T: l16 = slice
            int lm = t >> 4, n8 = t & 15;
            const int* cp = Cm + (size_t)(b * LSEQ + z * CS + slice * 16 + lm) * NDIM + n8 * 8;
            int4 c0 = *(const int4*)cp;
            int4 c1 = *(const int4*)(cp + 4);
            half8 v;
            v[0] = (_Float16)(float)c0.x; v[1] = (_Float16)(float)c0.y;
            v[2] = (_Float16)(float)c0.z; v[3] = (_Float16)(float)c0.w;
            v[4] = (_Float16)(float)c1.x; v[5] = (_Float16)(float)c1.y;
            v[6] = (_Float16)(float)c1.z; v[7] = (_Float16)(float)c1.w;
            *(half8*)(C16T + ((size_t)(bz * 16 + slice) * 16 + n8) * 128 + lm * 8) = v;
        }
        publish(&fA2[bid2], t);
        return;
    }

    // ================= k56 (round-5 verified body, 1024 blocks) =================
    {
        int bid3 = blockIdx.x - 1696;
        int par = bid3 & 1;
        int id = bid3 >> 1;
        int h = id & 31, z = (id >> 5) & 7, b = id >> 8;
        int bz = b * NC + z, bzh = bz * H + h;

        // spin: k013 blocks (b, u<=z, h, half 0/1) + kA2's 26 blocks for this bz
        int nf = 2 * (z + 1);
        if (t < nf) {
            int u = t >> 1, hf = t & 1;
            spin_eq(&f013[((((b << 3) | u) << 5 | h) << 1) | hf], MAGIC);
        } else if (t < nf + 26) {
            spin_eq(&fA2[bz * 26 + (t - nf)], MAGIC);
        }
        __syncthreads();

        float* cumL = (float*)USH;
        _Float16* xT = (_Float16*)(USH + 1024);
        float (*ep)[65] = (float(*)[65])(USH + 1024);
        cumL[t] = cum[(size_t)bzh * CS + t];
        float cav = cAg[(size_t)bzh * CS + t];

        // phase 1: x8 row t -> xT tiled f16
        {
            const signed char* xrow = x8 + ((size_t)(b * LSEQ + z * CS + t) * H + h) * PDIM;
            int s8 = t >> 3, sj = t & 7;
            int4 r4 = *(const int4*)xrow;
            int4 r5 = *(const int4*)(xrow + 16);
            int4 r6 = *(const int4*)(xrow + 32);
            int4 r7 = *(const int4*)(xrow + 48);
            int words[16] = {r4.x, r4.y, r4.z, r4.w, r5.x, r5.y, r5.z, r5.w,
                             r6.x, r6.y, r6.z, r6.w, r7.x, r7.y, r7.z, r7.w};
#pragma unroll
            for (int wi = 0; wi < 16; ++wi) {
                int wv = words[wi];
#pragma unroll
                for (int bi = 0; bi < 4; ++bi) {
                    int p = wi * 4 + bi;
                    int val = (wv << (24 - 8 * bi)) >> 24;
                    xT[((p >> 4) * 32 + s8) * XT_PITCH + (p & 15) * 8 + sj] =
                        (_Float16)((float)val * cav);
                }
            }
        }
        __syncthreads();

        int w = t >> 6, lane = t & 63, m = lane & 15, q = lane >> 4;
        floatx4 acc[2][4] = {};   // [jl][pt], l16 = 4*par + 8*jl + w

        // inter phase: inline weighted z-scan of statesF16 + C MFMA
        bool interact[2];
#pragma unroll
        for (int jl = 0; jl < 2; ++jl) interact[jl] = (cumL[(4 * par + 8 * jl + w) * 16] > -80.f);
        const _Float16* cbase = C16T + (size_t)bz * 16 * 16 * 128 + m * 8;
        if (z > 0 && (interact[0] || interact[1])) {
            const float* cdb = cdecay + (size_t)b * NC * H + h;
            for (int kk = 0; kk < 4; ++kk) {
                int n8 = kk * 4 + q;
                half8 bf[4] = {};
                float wsc = 1.f;
                for (int u = z - 1; u >= 0; --u) {
                    if (wsc < 1e-8f) break;
                    _Float16 wh = (_Float16)wsc;
                    const _Float16* sfb = statesF16 + ((size_t)((b * NC + u) * H) + h) * 8192 + m * 8;
#pragma unroll
                    for (int pt = 0; pt < 4; ++pt) {
                        half8 fr = *(const half8*)(sfb + (pt * 16 + n8) * 128);
                        bf[pt] += fr * wh;
                    }
                    wsc *= cdb[(size_t)u * H];
                }
#pragma unroll
                for (int jl = 0; jl < 2; ++jl) {
                    if (!interact[jl]) continue;
                    int l16 = 4 * par + 8 * jl + w;
                    half8 ha = *(const half8*)(cbase + ((size_t)l16 * 16 + n8) * 128);
#pragma unroll
                    for (int pt = 0; pt < 4; ++pt)
                        acc[jl][pt] = __builtin_amdgcn_mfma_f32_16x16x32_f16(ha, bf[pt], acc[jl][pt], 0, 0, 0);
                }
            }
        }
        float Cs16 = (*Cs_p) * 16.0f;
#pragma unroll
        for (int jl = 0; jl < 2; ++jl)
#pragma unroll
            for (int r = 0; r < 4; ++r) {
                float e = __expf(cumL[(4 * par + 8 * jl + w) * 16 + q * 4 + r]) * Cs16;
#pragma unroll
                for (int pt = 0; pt < 4; ++pt) acc[jl][pt][r] *= e;
            }

        // intra phase (causal: active iff l16 >= 2*kk)
        const _Float16* cbtb = CBh + (size_t)bz * 16 * 32 * 128 + m * 8;
        int l16max = 4 * par + 8 + w;
        for (int kk = 0; kk < 8; ++kk) {
            if (l16max < 2 * kk) continue;
            int s8 = kk * 4 + q;
            half8 bf[4];
#pragma unroll
            for (int pt = 0; pt < 4; ++pt)
                bf[pt] = *(const half8*)(xT + (size_t)(pt * 32 + s8) * XT_PITCH + m * 8);
            floatx4 c0 = *(const floatx4*)(&cumL[kk * 32 + q * 8]);
            floatx4 c1 = *(const floatx4*)(&cumL[kk * 32 + q * 8 + 4]);
#pragma unroll
            for (int jl = 0; jl < 2; ++jl) {
                int l16 = 4 * par + 8 * jl + w;
                if (l16 < 2 * kk) continue;
                if (cumL[l16 * 16] - cumL[kk * 32 + 31] < -30.f) continue;
                int lA = l16 * 16 + m;
                float cum_l = cumL[lA];
                half8 cb8 = *(const half8*)(cbtb + ((size_t)l16 * 32 + s8) * 128);
                half8 a;
#pragma unroll
                for (int jj = 0; jj < 8; ++jj) {
                    int s = kk * 32 + q * 8 + jj;
                    float cls = (jj < 4) ? c0[jj] : c1[jj - 4];
                    float wv = (float)cb8[jj] * __expf(cum_l - cls);
                    a[jj] = (_Float16)((s <= lA) ? wv : 0.f);
                }
#pragma unroll
                for (int pt = 0; pt < 4; ++pt)
                    acc[jl][pt] = __builtin_amdgcn_mfma_f32_16x16x32_f16(a, bf[pt], acc[jl][pt], 0, 0, 0);
            }
        }

        // epilogue: LDS transpose -> coalesced float4 out, + D*x
        float xsDf = (*xs_p) * ((float)qD[h] * (*Ds_p));
        __syncthreads();   // xT dead from here; smem becomes ep
#pragma unroll
        for (int jl = 0; jl < 2; ++jl) {
            int lbase = jl * 64 + w * 16 + q * 4;
#pragma unroll
            for (int r = 0; r < 4; ++r)
#pragma unroll
                for (int pt = 0; pt < 4; ++pt)
                    ep[lbase + r][pt * 16 + m] = acc[jl][pt][r];
        }
        __syncthreads();
        {
            int lloc = t >> 1;
            int jl = lloc >> 6, wv = (lloc >> 4) & 3, lm = lloc & 15;
            int l = (4 * par + 8 * jl + wv) * 16 + lm;
            size_t go = ((size_t)(b * LSEQ + z * CS + l) * H + h) * PDIM + (t & 1) * 32;
            const float* er = &ep[lloc][(t & 1) * 32];
            const signed char* xp8 = x8 + go;
#pragma unroll
            for (int it = 0; it < 8; ++it) {
                int xw = *(const int*)(xp8 + it * 4);
                floatx4 vv;
                vv[0] = er[it * 4 + 0] + (float)((xw << 24) >> 24) * xsDf;
                vv[1] = er[it * 4 + 1] + (float)((xw << 16) >> 24) * xsDf;
                vv[2] = er[it * 4 + 2] + (float)((xw << 8) >> 24) * xsDf;
                vv[3] = er[it * 4 + 3] + (float)(xw >> 24) * xsDf;
                *(floatx4*)(out + go + it * 4) = vv;
            }
        }
    }
}

extern "C" void kernel_launch(void* const* d_in, const int* in_sizes, int n_in,
                              void* d_out, int out_size, void* d_ws, size_t ws_size,
                              hipStream_t stream)
{
    const int* xq = (const int*)d_in[0];
    const int* dt = (const int*)d_in[1];
    const int* Bm = (const int*)d_in[2];
    const int* Cm = (const int*)d_in[3];
    const int* qA = (const int*)d_in[4];
    const int* qD = (const int*)d_in[5];
    const float* dt_bias = (const float*)d_in[6];
    const float* A_scale = (const float*)d_in[7];
    const float* D_scale = (const float*)d_in[8];
    const float* dt_scale = (const float*)d_in[9];
    const float* x_scale = (const float*)d_in[10];
    const float* B_scale = (const float*)d_in[11];
    const float* C_scale = (const float*)d_in[12];
    float* out = (float*)d_out;

    char* ws = (char*)d_ws;
    float* cum           = (float*)(ws);
    float* cAg           = (float*)(ws + 524288);
    float* cdecay        = (float*)(ws + 1048576);
    _Float16* CBh        = (_Float16*)(ws + 1050624);
    _Float16* statesF16  = (_Float16*)(ws + 3147776);
    _Float16* Bt16T      = (_Float16*)(ws + 19924992);
    _Float16* C16T       = (_Float16*)(ws + 20973568);
    signed char* x8      = (signed char*)(ws + 22022144);
    int* fA1             = (int*)(ws + 30410752);
    int* f013            = (int*)(ws + 30411776);
    int* fA2             = (int*)(ws + 30415872);

    kMega<<<dim3(2720), dim3(256), 0, stream>>>(
        dt, qA, dt_bias, A_scale, dt_scale,
        xq, x_scale, B_scale,
        Bm, Cm, C_scale, qD, D_scale,
        cum, cAg, cdecay, x8, statesF16,
        Bt16T, CBh, C16T,
        fA1, f013, fA2,
        out);
}

// Round 9
// 148.540 us; speedup vs baseline: 2.0852x; 2.0852x over previous
//
#include <hip/hip_runtime.h>
#include <math.h>

#define BB 2
#define LSEQ 2048
#define H 32
#define PDIM 64
#define NDIM 128
#define CS 256
#define NC 8

typedef _Float16 half8 __attribute__((ext_vector_type(8)));
typedef _Float16 half4 __attribute__((ext_vector_type(4)));
typedef float floatx4 __attribute__((ext_vector_type(4)));

// ---------------- ws layout (bytes) ----------------
// cum      : f32 [bz=16][H][CS]               @ 0         (512 KB)
// cA       : f32 [bz][H][CS]  (dtf*xs)        @ 524288    (512 KB)
// cdecay   : f32 [bz][H]                      @ 1048576   (2 KB)
// CBh      : f16 [bz][l16=16][s8=32][16][8]   @ 1050624   (2 MB)  MFMA-tiled, causal only
// statesF16: f16 [bzh][8192] tiled /16        @ 3147776   (8 MB)  per-chunk states
// Bt16T    : f16 [bz][n16=8][s8=32][16][8]    @ 19924992  (1 MB)
// C16T     : f16 [bz][l16=16][n8=16][16][8]   @ 20973568  (1 MB)
// x8       : i8  [b][l][h][p]                 @ 22022144  (8 MB)

__device__ __forceinline__ int dot4i8(int a, int b, int c) {
#if __has_builtin(__builtin_amdgcn_sdot4)
    return __builtin_amdgcn_sdot4(a, b, c, false);
#else
    c += ((a << 24) >> 24) * ((b << 24) >> 24);
    c += ((a << 16) >> 24) * ((b << 16) >> 24);
    c += ((a << 8) >> 24) * ((b << 8) >> 24);
    c += (a >> 24) * (b >> 24);
    return c;
#endif
}

// kA1: Bt16T transpose ONLY — the sole dependency of k013. 256 blocks. (verified)
__global__ __launch_bounds__(256) void kA1(
    const int* __restrict__ Bm, _Float16* __restrict__ Bt16T)
{
    int t = threadIdx.x;
    int slice = blockIdx.x & 15;
    int zz = blockIdx.x >> 4;
    int z = zz & 7, b = zz >> 3;
    int bz = b * NC + z;
    int nm = t & 15, s8l = t >> 4;
    int n16 = slice & 7, s8 = (slice >> 3) * 16 + s8l;
    const int* bp = Bm + (size_t)(b * LSEQ + z * CS + s8 * 8) * NDIM + n16 * 16 + nm;
    half8 v;
#pragma unroll
    for (int j = 0; j < 8; ++j) v[j] = (_Float16)(float)bp[(size_t)j * NDIM];
    *(half8*)(Bt16T + ((size_t)(bz * 8 + n16) * 32 + s8) * 128 + nm * 8) = v;
}

// k013A2: one dispatch, two independent block families. (verified round 5)
//   blocks [0,1024)    : k013 — scan + x staging + states MFMA
//   blocks [1024,1440) : kA2 — CBh Gram + C16T prep (only needed by k56)
#define P16_STRIDE 4360   // 32*136 + 8 halfs: +8 skew keeps scatter <=2-way banked
__global__ __launch_bounds__(256, 4) void k013A2(
    const int* __restrict__ dt, const int* __restrict__ qA, const float* __restrict__ dt_bias,
    const float* __restrict__ A_scale_p, const float* __restrict__ dt_scale_p,
    const int* __restrict__ xq, const float* __restrict__ xs_p, const float* __restrict__ Bs_p,
    const _Float16* __restrict__ Bt16T,
    float* __restrict__ cum, float* __restrict__ cAg, float* __restrict__ cdecay,
    signed char* __restrict__ x8, _Float16* __restrict__ statesF16,
    const int* __restrict__ Bm, const int* __restrict__ Cm, const float* __restrict__ Cs_p,
    _Float16* __restrict__ CBh, _Float16* __restrict__ C16T)
{
    __shared__ __align__(16) char USH[19488];   // union: k013 19488B | kA2 16896B
    int t = threadIdx.x;
    if (blockIdx.x < 1024) {
        // ================= k013 =================
        float* cumS   = (float*)USH;             // 256 f32
        float* cB     = (float*)(USH + 1024);    // 256 f32
        float* wsum   = (float*)(USH + 2048);    // 4 f32
        _Float16* xcS = (_Float16*)(USH + 2064); // 8712 halfs
        int half = blockIdx.x & 1;
        int id = blockIdx.x >> 1;
        int h = id & 31, z = (id >> 5) & 7, b = id >> 8;
        int bz = b * NC + z, bzh = bz * H + h;
        int lane6 = t & 63, w = t >> 6;

        float A = -__expf((float)qA[h] * (*A_scale_p));
        float raw = (float)dt[(size_t)(b * LSEQ + z * CS + t) * H + h];
        float xin = raw * (*dt_scale_p) + dt_bias[h];
        float sp = (xin > 20.f) ? xin : log1pf(__expf(xin));
        float v = sp * A;
#pragma unroll
        for (int off = 1; off < 64; off <<= 1) {
            float u = __shfl_up(v, off, 64);
            if (lane6 >= off) v += u;
        }
        if (lane6 == 63) wsum[w] = v;
        __syncthreads();
        float add = 0.f;
        for (int wv = 0; wv < w; ++wv) add += wsum[wv];
        float cumv = v + add;
        float cl = wsum[0] + wsum[1] + wsum[2] + wsum[3];
        float xs = *xs_p;
        if (half == 0) {
            cum[(size_t)bzh * CS + t] = cumv;
            cAg[(size_t)bzh * CS + t] = sp * xs;
            if (t == 0) cdecay[bzh] = __expf(cl);
        }
        cumS[t] = cumv;
        cB[t] = sp * __expf(cl - cumv) * xs * (*Bs_p);
        __syncthreads();

        // coalesced x: 8 lanes x 16B cover this block's 32-p slice of a row
        int pq = t & 7, srow = t >> 3;
        int p0 = half * 32 + pq * 4;
        const int* xb = xq + ((size_t)(b * LSEQ + z * CS) * H + h) * PDIM + p0;
        signed char* x8b = x8 + ((size_t)(b * LSEQ + z * CS) * H + h) * PDIM + p0;
        int plocal = pq * 4;
        int pbase = (plocal >> 4) * P16_STRIDE + ((plocal & 15) * 8);
        for (int j = 0; j < 8; ++j) {
            int s = j * 32 + srow;
            int4 w4 = *(const int4*)(xb + (size_t)s * (H * PDIM));
            float c = cB[s];
            int sbase = pbase + (s >> 3) * 136 + (s & 7);
            signed char pk[4];
            int xi[4] = {w4.x, w4.y, w4.z, w4.w};
#pragma unroll
            for (int pp = 0; pp < 4; ++pp) {
                xcS[sbase + pp * 8] = (_Float16)((float)xi[pp] * c);
                pk[pp] = (signed char)xi[pp];
            }
            *(int*)(x8b + (size_t)s * (H * PDIM)) = *(int*)pk;
        }
        __syncthreads();

        // states MFMA: wave w -> p16l = w&1, n-tile half = w>>1 (4 nt each)
        int m = lane6 & 15, q = lane6 >> 4;
        int p16l = w & 1, ntb = (w >> 1) * 4;
        const _Float16* abase = xcS + p16l * P16_STRIDE + m * 8;
        const _Float16* bbase = Bt16T + (size_t)(bz * 8) * 32 * 128 + m * 8;
        floatx4 acc[4] = {};
        for (int kk = 0; kk < 8; ++kk) {
            if (cl - cumS[kk * 32 + 31] < -30.f) continue;   // fp16-exact-0 chunk skip
            int s8k = kk * 4 + q;
            half8 a = *(const half8*)(abase + s8k * 136);
#pragma unroll
            for (int nt = 0; nt < 4; ++nt) {
                half8 bf = *(const half8*)(bbase + ((size_t)(ntb + nt) * 32 + s8k) * 128);
                acc[nt] = __builtin_amdgcn_mfma_f32_16x16x32_f16(a, bf, acc[nt], 0, 0, 0);
            }
        }
        int p16g = half * 2 + p16l;
        _Float16* sb = statesF16 + (size_t)bzh * 8192;
#pragma unroll
        for (int nt = 0; nt < 4; ++nt)
#pragma unroll
            for (int rr = 0; rr < 4; ++rr)
                sb[(size_t)(p16g * 16 + (ntb + nt) * 2 + (m >> 3)) * 128 + (q * 4 + rr) * 8 + (m & 7)] =
                    (_Float16)(acc[nt][rr] * 0.0625f);
        return;
    }
    // ================= kA2: CBh Gram + C16T =================
    {
        int (*Bi)[33] = (int(*)[33])USH;
        int (*Ci)[33] = (int(*)[33])(USH + 8448);
        int bid2 = blockIdx.x - 1024;
        int r = bid2 % 26;
        int zz = bid2 / 26;
        int z = zz & 7, b = zz >> 3;
        int bz = b * NC + z;
        if (r < 10) {
            const int LT[10] = {0,1,1,2,2,2,3,3,3,3};
            const int ST[10] = {0,0,1,0,1,2,0,1,2,3};
            int l0 = LT[r] * 64, s0 = ST[r] * 64;
            const int* Bp = Bm + (size_t)(b * LSEQ + z * CS + s0) * NDIM;
            const int* Cp = Cm + (size_t)(b * LSEQ + z * CS + l0) * NDIM;
            for (int i = t; i < 64 * 32; i += 256) {
                int rr = i >> 5, k = i & 31;
                const int* sb = Bp + rr * NDIM + k * 4;
                const int* sc = Cp + rr * NDIM + k * 4;
                Bi[rr][k] = (sb[0] & 255) | ((sb[1] & 255) << 8) | ((sb[2] & 255) << 16) | ((sb[3] & 255) << 24);
                Ci[rr][k] = (sc[0] & 255) | ((sc[1] & 255) << 8) | ((sc[2] & 255) << 16) | ((sc[3] & 255) << 24);
            }
            __syncthreads();
            float cbscale = (*Bs_p) * (*Cs_p);
            int ll = t & 63, lg = t >> 6;
            int acc[16];
#pragma unroll
            for (int i = 0; i < 16; ++i) acc[i] = 0;
            for (int k = 0; k < 32; ++k) {
                int cw = Ci[ll][k];
#pragma unroll
                for (int si = 0; si < 16; ++si)
                    acc[si] = dot4i8(cw, Bi[lg * 16 + si][k], acc[si]);
            }
            int l = l0 + ll;
            int l16 = l >> 4, lm = l & 15;
            int sb8 = (s0 + lg * 16) >> 3;
            _Float16* bp = CBh + ((size_t)(bz * 16 + l16) * 32 + sb8) * 128 + lm * 8;
#pragma unroll
            for (int g = 0; g < 2; ++g) {
                half8 v;
#pragma unroll
                for (int i = 0; i < 8; ++i) v[i] = (_Float16)((float)acc[g * 8 + i] * cbscale);
                *(half8*)(bp + g * 128) = v;
            }
        } else {
            int slice = r - 10;   // 0..15 -> C16T: l16 = slice
            int lm = t >> 4, n8 = t & 15;
            const int* cp = Cm + (size_t)(b * LSEQ + z * CS + slice * 16 + lm) * NDIM + n8 * 8;
            int4 c0 = *(const int4*)cp;
            int4 c1 = *(const int4*)(cp + 4);
            half8 v;
            v[0] = (_Float16)(float)c0.x; v[1] = (_Float16)(float)c0.y;
            v[2] = (_Float16)(float)c0.z; v[3] = (_Float16)(float)c0.w;
            v[4] = (_Float16)(float)c1.x; v[5] = (_Float16)(float)c1.y;
            v[6] = (_Float16)(float)c1.z; v[7] = (_Float16)(float)c1.w;
            *(half8*)(C16T + ((size_t)(bz * 16 + slice) * 16 + n8) * 128 + lm * 8) = v;
        }
    }
}

// k56: fused inter+intra+D with INLINE z-scan (k4 eliminated). (verified round 5)
// prefix(z) = sum_{u<z} W_u * states[u], W_u = prod_{v=u+1}^{z-1} cdecay[v];
// computed as order-free weighted sum in packed f16, terms with W<1e-8 skipped.
#define XT_PITCH 136
__global__ __launch_bounds__(256, 4) void k56(
    const signed char* __restrict__ x8, const int* __restrict__ qD,
    const float* __restrict__ cum, const float* __restrict__ cAg,
    const float* __restrict__ cdecay,
    const _Float16* __restrict__ CBh, const _Float16* __restrict__ C16T,
    const _Float16* __restrict__ statesF16,
    const float* __restrict__ Cs_p, const float* __restrict__ xs_p, const float* __restrict__ Ds_p,
    float* __restrict__ out)
{
    __shared__ float cumL[CS];
    __shared__ __align__(16) char smem[4 * 32 * XT_PITCH * 2];   // 34816B: xT, later ep
    _Float16* xT = (_Float16*)smem;
    float (*ep)[65] = (float(*)[65])smem;                        // 33280B alias
    int t = threadIdx.x;
    int par = blockIdx.x & 1;
    int id = blockIdx.x >> 1;
    int h = id & 31, z = (id >> 5) & 7, b = id >> 8;
    int bz = b * NC + z, bzh = bz * H + h;
    cumL[t] = cum[(size_t)bzh * CS + t];
    float cav = cAg[(size_t)bzh * CS + t];

    // --- phase 1: x8 row t (coalesced 64B/lane) -> xT[p][s]*(dtf*xs), tiled f16 ---
    {
        const signed char* xrow = x8 + ((size_t)(b * LSEQ + z * CS + t) * H + h) * PDIM;
        int s8 = t >> 3, sj = t & 7;
        int4 r4 = *(const int4*)xrow;
        int4 r5 = *(const int4*)(xrow + 16);
        int4 r6 = *(const int4*)(xrow + 32);
        int4 r7 = *(const int4*)(xrow + 48);
        int words[16] = {r4.x, r4.y, r4.z, r4.w, r5.x, r5.y, r5.z, r5.w,
                         r6.x, r6.y, r6.z, r6.w, r7.x, r7.y, r7.z, r7.w};
#pragma unroll
        for (int wi = 0; wi < 16; ++wi) {
            int wv = words[wi];
#pragma unroll
            for (int bi = 0; bi < 4; ++bi) {
                int p = wi * 4 + bi;
                int val = (wv << (24 - 8 * bi)) >> 24;
                xT[((p >> 4) * 32 + s8) * XT_PITCH + (p & 15) * 8 + sj] =
                    (_Float16)((float)val * cav);
            }
        }
    }
    __syncthreads();

    int w = t >> 6, lane = t & 63, m = lane & 15, q = lane >> 4;
    floatx4 acc[2][4] = {};   // [jl][pt], l16 = 4*par + 8*jl + w

    // ---- inter phase: inline weighted z-scan of statesF16 + C MFMA ----
    bool interact[2];
#pragma unroll
    for (int jl = 0; jl < 2; ++jl) interact[jl] = (cumL[(4 * par + 8 * jl + w) * 16] > -80.f);
    const _Float16* cbase = C16T + (size_t)bz * 16 * 16 * 128 + m * 8;
    if (z > 0 && (interact[0] || interact[1])) {
        const float* cdb = cdecay + (size_t)b * NC * H + h;
        for (int kk = 0; kk < 4; ++kk) {
            int n8 = kk * 4 + q;
            half8 bf[4] = {};
            float wsc = 1.f;
            for (int u = z - 1; u >= 0; --u) {
                if (wsc < 1e-8f) break;
                _Float16 wh = (_Float16)wsc;
                const _Float16* sfb = statesF16 + ((size_t)((b * NC + u) * H) + h) * 8192 + m * 8;
#pragma unroll
                for (int pt = 0; pt < 4; ++pt) {
                    half8 fr = *(const half8*)(sfb + (pt * 16 + n8) * 128);
                    bf[pt] += fr * wh;
                }
                wsc *= cdb[(size_t)u * H];
            }
#pragma unroll
            for (int jl = 0; jl < 2; ++jl) {
                if (!interact[jl]) continue;
                int l16 = 4 * par + 8 * jl + w;
                half8 ha = *(const half8*)(cbase + ((size_t)l16 * 16 + n8) * 128);
#pragma unroll
                for (int pt = 0; pt < 4; ++pt)
                    acc[jl][pt] = __builtin_amdgcn_mfma_f32_16x16x32_f16(ha, bf[pt], acc[jl][pt], 0, 0, 0);
            }
        }
    }
    float Cs16 = (*Cs_p) * 16.0f;
#pragma unroll
    for (int jl = 0; jl < 2; ++jl)
#pragma unroll
        for (int r = 0; r < 4; ++r) {
            float e = __expf(cumL[(4 * par + 8 * jl + w) * 16 + q * 4 + r]) * Cs16;
#pragma unroll
            for (int pt = 0; pt < 4; ++pt) acc[jl][pt][r] *= e;
        }

    // ---- intra phase (causal: active iff l16 >= 2*kk) ----
    const _Float16* cbtb = CBh + (size_t)bz * 16 * 32 * 128 + m * 8;
    int l16max = 4 * par + 8 + w;
    for (int kk = 0; kk < 8; ++kk) {
        if (l16max < 2 * kk) continue;
        int s8 = kk * 4 + q;
        half8 bf[4];
#pragma unroll
        for (int pt = 0; pt < 4; ++pt)
            bf[pt] = *(const half8*)(xT + (size_t)(pt * 32 + s8) * XT_PITCH + m * 8);
        floatx4 c0 = *(const floatx4*)(&cumL[kk * 32 + q * 8]);
        floatx4 c1 = *(const floatx4*)(&cumL[kk * 32 + q * 8 + 4]);
#pragma unroll
        for (int jl = 0; jl < 2; ++jl) {
            int l16 = 4 * par + 8 * jl + w;
            if (l16 < 2 * kk) continue;
            if (cumL[l16 * 16] - cumL[kk * 32 + 31] < -30.f) continue;
            int lA = l16 * 16 + m;
            float cum_l = cumL[lA];
            half8 cb8 = *(const half8*)(cbtb + ((size_t)l16 * 32 + s8) * 128);
            half8 a;
#pragma unroll
            for (int jj = 0; jj < 8; ++jj) {
                int s = kk * 32 + q * 8 + jj;
                float cls = (jj < 4) ? c0[jj] : c1[jj - 4];
                float wv = (float)cb8[jj] * __expf(cum_l - cls);
                a[jj] = (_Float16)((s <= lA) ? wv : 0.f);
            }
#pragma unroll
            for (int pt = 0; pt < 4; ++pt)
                acc[jl][pt] = __builtin_amdgcn_mfma_f32_16x16x32_f16(a, bf[pt], acc[jl][pt], 0, 0, 0);
        }
    }

    // ---- epilogue: LDS transpose (aliases xT) -> coalesced float4 out, + D*x ----
    float xsDf = (*xs_p) * ((float)qD[h] * (*Ds_p));
    __syncthreads();   // xT dead from here; smem becomes ep
#pragma unroll
    for (int jl = 0; jl < 2; ++jl) {
        int lbase = jl * 64 + w * 16 + q * 4;    // local row 0..127
#pragma unroll
        for (int r = 0; r < 4; ++r)
#pragma unroll
            for (int pt = 0; pt < 4; ++pt)
                ep[lbase + r][pt * 16 + m] = acc[jl][pt][r];
    }
    __syncthreads();
    {
        int lloc = t >> 1;                        // 0..127
        int jl = lloc >> 6, wv = (lloc >> 4) & 3, lm = lloc & 15;
        int l = (4 * par + 8 * jl + wv) * 16 + lm;
        size_t go = ((size_t)(b * LSEQ + z * CS + l) * H + h) * PDIM + (t & 1) * 32;
        const float* er = &ep[lloc][(t & 1) * 32];
        const signed char* xp8 = x8 + go;
#pragma unroll
        for (int it = 0; it < 8; ++it) {
            int xw = *(const int*)(xp8 + it * 4);
            floatx4 vv;
            vv[0] = er[it * 4 + 0] + (float)((xw << 24) >> 24) * xsDf;
            vv[1] = er[it * 4 + 1] + (float)((xw << 16) >> 24) * xsDf;
            vv[2] = er[it * 4 + 2] + (float)((xw << 8) >> 24) * xsDf;
            vv[3] = er[it * 4 + 3] + (float)(xw >> 24) * xsDf;
            *(floatx4*)(out + go + it * 4) = vv;
        }
    }
}

extern "C" void kernel_launch(void* const* d_in, const int* in_sizes, int n_in,
                              void* d_out, int out_size, void* d_ws, size_t ws_size,
                              hipStream_t stream)
{
    const int* xq = (const int*)d_in[0];
    const int* dt = (const int*)d_in[1];
    const int* Bm = (const int*)d_in[2];
    const int* Cm = (const int*)d_in[3];
    const int* qA = (const int*)d_in[4];
    const int* qD = (const int*)d_in[5];
    const float* dt_bias = (const float*)d_in[6];
    const float* A_scale = (const float*)d_in[7];
    const float* D_scale = (const float*)d_in[8];
    const float* dt_scale = (const float*)d_in[9];
    const float* x_scale = (const float*)d_in[10];
    const float* B_scale = (const float*)d_in[11];
    const float* C_scale = (const float*)d_in[12];
    float* out = (float*)d_out;

    char* ws = (char*)d_ws;
    float* cum           = (float*)(ws);
    float* cAg           = (float*)(ws + 524288);
    float* cdecay        = (float*)(ws + 1048576);
    _Float16* CBh        = (_Float16*)(ws + 1050624);
    _Float16* statesF16  = (_Float16*)(ws + 3147776);
    _Float16* Bt16T      = (_Float16*)(ws + 19924992);
    _Float16* C16T       = (_Float16*)(ws + 20973568);
    signed char* x8      = (signed char*)(ws + 22022144);

    kA1<<<dim3(256), dim3(256), 0, stream>>>(Bm, Bt16T);
    k013A2<<<dim3(1440), dim3(256), 0, stream>>>(dt, qA, dt_bias, A_scale, dt_scale,
                                                 xq, x_scale, B_scale, Bt16T,
                                                 cum, cAg, cdecay, x8, statesF16,
                                                 Bm, Cm, C_scale, CBh, C16T);
    k56<<<dim3(1024), dim3(256), 0, stream>>>(x8, qD, cum, cAg, cdecay, CBh, C16T,
                                              statesF16, C_scale, x_scale, D_scale, out);
}